// Round 1
// baseline (7438.271 us; speedup 1.0000x reference)
//
#include <hip/hip_runtime.h>
#include <cstdint>

#define T_STEPS 1024
#define I_DIM 128
#define H_DIM 256
// grid: 256 blocks = 16 column-slices (cwg) x 16 row-groups (grp); 256 threads = 4 waves = 4 gates

typedef __attribute__((ext_vector_type(8))) short bf16x8;
typedef __attribute__((ext_vector_type(4))) float f32x4;

__device__ __forceinline__ uint32_t f2bf(float f) {
    uint32_t u = __builtin_bit_cast(uint32_t, f);
    return (u + 0x7FFFu + ((u >> 16) & 1u)) >> 16;   // RNE
}
__device__ __forceinline__ uint32_t pk2bf(float lo, float hi) {
    return (f2bf(lo) & 0xFFFFu) | (f2bf(hi) << 16);
}
__device__ __forceinline__ float sigmoid_(float v) { return 1.f / (1.f + __expf(-v)); }
__device__ __forceinline__ float tanh_(float v) { float e = __expf(2.f * v); return 1.f - 2.f / (e + 1.f); }

__global__ void __launch_bounds__(256, 1)
lstm_kernel(const float* __restrict__ x,
            const float* __restrict__ f_wh, const float* __restrict__ f_wx, const float* __restrict__ f_b,
            const float* __restrict__ p_wh, const float* __restrict__ p_wx, const float* __restrict__ p_b,
            const float* __restrict__ c_wh, const float* __restrict__ c_wx, const float* __restrict__ c_b,
            const float* __restrict__ o_wh, const float* __restrict__ o_wx, const float* __restrict__ o_b,
            float* __restrict__ out, uint32_t* __restrict__ ws_cnt, uint32_t* __restrict__ sbuf)
{
    __shared__ __align__(16) uint8_t lds[61440];
    uint8_t* WH = lds;                    // [4 gates][16 cols][256 k] bf16, XOR-swizzled   (32768 B)
    uint8_t* WX = lds + 32768;            // [4 gates][16 cols][128 k] bf16, swizzled       (16384 B)
    uint8_t* SL = lds + 49152;            // s tile [16][256] bf16 swz (8192 B); xt tile [16][128] aliased in same bytes
    float*   GB = (float*)(lds + 57344);  // activated gates [4][16][16] f32                 (4096 B)

    const int tid  = (int)threadIdx.x;
    const int lane = tid & 63;
    const int wv   = tid >> 6;            // 0=forget,1=pot(tanh),2=perc,3=out
    const int blk  = (int)blockIdx.x;
    const int grp  = blk & 15;            // row-group; members blk%16==grp land on same XCD under round-robin
    const int cwg  = blk >> 4;            // column slice
    const int grow0 = grp << 4;           // first batch row
    const int hc0   = cwg << 4;           // first H column

    uint32_t* cnt = ws_cnt + grp * 32;    // one counter per group, 128B apart

    const float* wh = (wv == 0) ? f_wh : (wv == 1) ? p_wh : (wv == 2) ? c_wh : o_wh;
    const float* wx = (wv == 0) ? f_wx : (wv == 1) ? p_wx : (wv == 2) ? c_wx : o_wx;
    const float* bp = (wv == 0) ? f_b  : (wv == 1) ? p_b  : (wv == 2) ? c_b  : o_b;

    // ---- stage weights into LDS: layout [gate][col][k] bf16, byte-off XOR ((col&7)<<4) ----
    {
        const int col = lane & 15, kc = lane >> 4;
        const uint32_t csw = (uint32_t)((col & 7) << 4);
        uint8_t* whb = WH + (size_t)(wv * 16 + col) * 512;
        #pragma unroll
        for (int it = 0; it < 8; ++it) {
            const int k0 = it * 32 + kc * 8;
            float v0 = wh[(size_t)(k0 + 0) * H_DIM + hc0 + col];
            float v1 = wh[(size_t)(k0 + 1) * H_DIM + hc0 + col];
            float v2 = wh[(size_t)(k0 + 2) * H_DIM + hc0 + col];
            float v3 = wh[(size_t)(k0 + 3) * H_DIM + hc0 + col];
            float v4 = wh[(size_t)(k0 + 4) * H_DIM + hc0 + col];
            float v5 = wh[(size_t)(k0 + 5) * H_DIM + hc0 + col];
            float v6 = wh[(size_t)(k0 + 6) * H_DIM + hc0 + col];
            float v7 = wh[(size_t)(k0 + 7) * H_DIM + hc0 + col];
            uint4 pk;
            pk.x = pk2bf(v0, v1); pk.y = pk2bf(v2, v3);
            pk.z = pk2bf(v4, v5); pk.w = pk2bf(v6, v7);
            *(uint4*)(whb + (((uint32_t)(it * 64 + kc * 16)) ^ csw)) = pk;
        }
        uint8_t* wxb = WX + (size_t)(wv * 16 + col) * 256;
        #pragma unroll
        for (int it = 0; it < 4; ++it) {
            const int k0 = it * 32 + kc * 8;
            float v0 = wx[(size_t)(k0 + 0) * H_DIM + hc0 + col];
            float v1 = wx[(size_t)(k0 + 1) * H_DIM + hc0 + col];
            float v2 = wx[(size_t)(k0 + 2) * H_DIM + hc0 + col];
            float v3 = wx[(size_t)(k0 + 3) * H_DIM + hc0 + col];
            float v4 = wx[(size_t)(k0 + 4) * H_DIM + hc0 + col];
            float v5 = wx[(size_t)(k0 + 5) * H_DIM + hc0 + col];
            float v6 = wx[(size_t)(k0 + 6) * H_DIM + hc0 + col];
            float v7 = wx[(size_t)(k0 + 7) * H_DIM + hc0 + col];
            uint4 pk;
            pk.x = pk2bf(v0, v1); pk.y = pk2bf(v2, v3);
            pk.z = pk2bf(v4, v5); pk.w = pk2bf(v6, v7);
            *(uint4*)(wxb + (((uint32_t)(it * 64 + kc * 16)) ^ csw)) = pk;
        }
    }
    const float bias = bp[hc0 + (lane & 15)];

    // combine-thread mapping: one (row,col) element per thread; l lives in a register
    const int crow = tid >> 4, ccol = tid & 15;
    const uint32_t pub_idx = (uint32_t)(grow0 + crow) * 128u + (uint32_t)cwg * 8u + (uint32_t)(ccol >> 1);

    // zero-publish p=0 (s(0)=0) into buffer 0
    if ((tid & 1) == 0)
        __hip_atomic_store(sbuf + pub_idx, 0u, __ATOMIC_RELAXED, __HIP_MEMORY_SCOPE_AGENT);
    __syncthreads();
    if (tid == 0)
        __hip_atomic_fetch_add(cnt, 1u, __ATOMIC_RELEASE, __HIP_MEMORY_SCOPE_AGENT);

    // x prefetch for t=0
    const int xrow = tid >> 4, xseg = tid & 15;
    const uint32_t xsw = (uint32_t)((xrow & 7) << 4);
    const float* xptr = x + (size_t)(grow0 + xrow) * (T_STEPS * I_DIM) + xseg * 8;
    float4 xr0 = *(const float4*)(xptr);
    float4 xr1 = *(const float4*)(xptr + 4);

    // per-lane fragment bases (A row / B col both = lane&15)
    const int fr = lane & 15, fkc = lane >> 4;
    const uint32_t fsw = (uint32_t)((fr & 7) << 4);
    uint8_t* slA = SL + (size_t)fr * 512;
    uint8_t* xtA = SL + (size_t)fr * 256;
    uint8_t* whB = WH + (size_t)(wv * 16 + fr) * 512;
    uint8_t* wxB = WX + (size_t)(wv * 16 + fr) * 256;

    float l_reg = 0.f, s_fin = 0.f, l_fin = 0.f;

    for (int t = 0; t < T_STEPS; ++t) {
        // stage xt(t) (bf16) into the XT alias region (off the s critical path)
        {
            uint4 pk;
            pk.x = pk2bf(xr0.x, xr0.y); pk.y = pk2bf(xr0.z, xr0.w);
            pk.z = pk2bf(xr1.x, xr1.y); pk.w = pk2bf(xr1.z, xr1.w);
            *(uint4*)(SL + (size_t)xrow * 256 + (((uint32_t)(xseg * 16)) ^ xsw)) = pk;
        }
        // prefetch x(t+1)
        {
            const int tn = (t + 1 < T_STEPS) ? (t + 1) : (T_STEPS - 1);
            const float* p = xptr + (size_t)tn * I_DIM;
            xr0 = *(const float4*)(p);
            xr1 = *(const float4*)(p + 4);
        }
        __syncthreads();  // xt tile ready
        // x-part MFMAs (independent of s)
        f32x4 acc = {0.f, 0.f, 0.f, 0.f};
        #pragma unroll
        for (int q = 0; q < 4; ++q) {
            const uint32_t o = (uint32_t)(q * 64 + fkc * 16);
            uint4 av = *(const uint4*)(xtA + (o ^ fsw));
            uint4 bv = *(const uint4*)(wxB + (o ^ fsw));
            acc = __builtin_amdgcn_mfma_f32_16x16x32_bf16(
                __builtin_bit_cast(bf16x8, av), __builtin_bit_cast(bf16x8, bv), acc, 0, 0, 0);
        }
        // wait until all 16 WGs of this group published s(t)
        if (tid == 0) {
            const uint32_t target = 16u * (uint32_t)(t + 1);
            while (__hip_atomic_load(cnt, __ATOMIC_RELAXED, __HIP_MEMORY_SCOPE_AGENT) < target) {}
            __builtin_amdgcn_fence(__ATOMIC_ACQUIRE, "agent");
        }
        __syncthreads();
        // gather s(t) -> SL (agent-scope loads from the coherent point)
        {
            const uint32_t* src = sbuf + (size_t)(t & 1) * 32768 + (size_t)(grow0 + xrow) * 128 + xseg * 8;
            uint32_t v0 = __hip_atomic_load(src + 0, __ATOMIC_RELAXED, __HIP_MEMORY_SCOPE_AGENT);
            uint32_t v1 = __hip_atomic_load(src + 1, __ATOMIC_RELAXED, __HIP_MEMORY_SCOPE_AGENT);
            uint32_t v2 = __hip_atomic_load(src + 2, __ATOMIC_RELAXED, __HIP_MEMORY_SCOPE_AGENT);
            uint32_t v3 = __hip_atomic_load(src + 3, __ATOMIC_RELAXED, __HIP_MEMORY_SCOPE_AGENT);
            uint32_t v4 = __hip_atomic_load(src + 4, __ATOMIC_RELAXED, __HIP_MEMORY_SCOPE_AGENT);
            uint32_t v5 = __hip_atomic_load(src + 5, __ATOMIC_RELAXED, __HIP_MEMORY_SCOPE_AGENT);
            uint32_t v6 = __hip_atomic_load(src + 6, __ATOMIC_RELAXED, __HIP_MEMORY_SCOPE_AGENT);
            uint32_t v7 = __hip_atomic_load(src + 7, __ATOMIC_RELAXED, __HIP_MEMORY_SCOPE_AGENT);
            uint8_t* dst = SL + (size_t)xrow * 512;
            const uint32_t o = (uint32_t)(xseg * 32);
            uint4 w0; w0.x = v0; w0.y = v1; w0.z = v2; w0.w = v3;
            uint4 w1; w1.x = v4; w1.y = v5; w1.z = v6; w1.w = v7;
            *(uint4*)(dst + (o ^ xsw)) = w0;
            *(uint4*)(dst + ((o + 16) ^ xsw)) = w1;
        }
        __syncthreads();  // s tile ready
        // recurrent MFMAs
        #pragma unroll
        for (int q = 0; q < 8; ++q) {
            const uint32_t o = (uint32_t)(q * 64 + fkc * 16);
            uint4 av = *(const uint4*)(slA + (o ^ fsw));
            uint4 bv = *(const uint4*)(whB + (o ^ fsw));
            acc = __builtin_amdgcn_mfma_f32_16x16x32_bf16(
                __builtin_bit_cast(bf16x8, av), __builtin_bit_cast(bf16x8, bv), acc, 0, 0, 0);
        }
        // bias + activation -> GB   (D layout: col=lane&15, row=(lane>>4)*4+j)
        #pragma unroll
        for (int j = 0; j < 4; ++j) {
            const float pre = acc[j] + bias;
            const float a = (wv == 1) ? tanh_(pre) : sigmoid_(pre);
            GB[wv * 256 + (fkc * 4 + j) * 16 + fr] = a;
        }
        __syncthreads();  // all gates ready
        // combine (1 element per thread) + publish s_new slice
        {
            const float fg  = GB[0 * 256 + crow * 16 + ccol];
            const float pot = GB[1 * 256 + crow * 16 + ccol];
            const float prc = GB[2 * 256 + crow * 16 + ccol];
            const float og  = GB[3 * 256 + crow * 16 + ccol];
            const float lnew = fg * l_reg + prc * pot;
            const float snew = tanh_(lnew) * og;
            l_reg = lnew;
            if (t == T_STEPS - 1) { s_fin = snew; l_fin = lnew; }
            const uint32_t sb = f2bf(snew);
            const uint32_t ob = (uint32_t)__shfl_xor((int)sb, 1, 64);
            if (((tid & 1) == 0) && (t != T_STEPS - 1)) {
                const uint32_t pkd = (sb & 0xFFFFu) | (ob << 16);
                __hip_atomic_store(sbuf + (size_t)((t + 1) & 1) * 32768 + pub_idx, pkd,
                                   __ATOMIC_RELAXED, __HIP_MEMORY_SCOPE_AGENT);
            }
        }
        if (t != T_STEPS - 1) {
            __syncthreads();  // barrier drains vmcnt -> all publish stores at coherent point
            if (tid == 0)
                __hip_atomic_fetch_add(cnt, 1u, __ATOMIC_RELEASE, __HIP_MEMORY_SCOPE_AGENT);
        }
    }

    // outputs: short_term then long_term, [256][256] f32 each
    out[(size_t)(grow0 + crow) * H_DIM + hc0 + ccol] = s_fin;
    out[(size_t)H_DIM * H_DIM + (size_t)(grow0 + crow) * H_DIM + hc0 + ccol] = l_fin;
}

extern "C" void kernel_launch(void* const* d_in, const int* in_sizes, int n_in,
                              void* d_out, int out_size, void* d_ws, size_t ws_size,
                              hipStream_t stream) {
    const float* x    = (const float*)d_in[0];
    const float* f_wh = (const float*)d_in[1];
    const float* f_wx = (const float*)d_in[2];
    const float* f_b  = (const float*)d_in[3];
    const float* p_wh = (const float*)d_in[4];
    const float* p_wx = (const float*)d_in[5];
    const float* p_b  = (const float*)d_in[6];
    const float* c_wh = (const float*)d_in[7];
    const float* c_wx = (const float*)d_in[8];
    const float* c_b  = (const float*)d_in[9];
    const float* o_wh = (const float*)d_in[10];
    const float* o_wx = (const float*)d_in[11];
    const float* o_b  = (const float*)d_in[12];
    float* outp = (float*)d_out;
    uint32_t* cnt  = (uint32_t*)d_ws;
    uint32_t* sbuf = (uint32_t*)((char*)d_ws + 4096);   // 2 x 256x256 bf16 = 256 KiB

    // counters must be zero every call (graph replays)
    hipMemsetAsync(d_ws, 0, 4096, stream);

    void* args[] = { (void*)&x,
                     (void*)&f_wh, (void*)&f_wx, (void*)&f_b,
                     (void*)&p_wh, (void*)&p_wx, (void*)&p_b,
                     (void*)&c_wh, (void*)&c_wx, (void*)&c_b,
                     (void*)&o_wh, (void*)&o_wx, (void*)&o_b,
                     (void*)&outp, (void*)&cnt, (void*)&sbuf };
    hipLaunchCooperativeKernel((const void*)lstm_kernel, dim3(256), dim3(256), args, 0, stream);
}

// Round 2
// 2300.885 us; speedup vs baseline: 3.2328x; 3.2328x over previous
//
#include <hip/hip_runtime.h>
#include <cstdint>

#define T_STEPS 1024
#define I_DIM 128
#define H_DIM 256
// grid: 256 blocks = 16 column-slices (cwg) x 16 row-groups (grp); 256 threads = 4 waves = 4 gates

typedef __attribute__((ext_vector_type(8))) short bf16x8;
typedef __attribute__((ext_vector_type(4))) float f32x4;

__device__ __forceinline__ uint32_t f2bf(float f) {
    uint32_t u = __builtin_bit_cast(uint32_t, f);
    return (u + 0x7FFFu + ((u >> 16) & 1u)) >> 16;   // RNE
}
__device__ __forceinline__ uint32_t pk2bf(float lo, float hi) {
    return (f2bf(lo) & 0xFFFFu) | (f2bf(hi) << 16);
}
__device__ __forceinline__ float sigmoid_(float v) { return 1.f / (1.f + __expf(-v)); }
__device__ __forceinline__ float tanh_(float v) { float e = __expf(2.f * v); return 1.f - 2.f / (e + 1.f); }

__global__ void __launch_bounds__(256, 1)
lstm_kernel(const float* __restrict__ x,
            const float* __restrict__ f_wh, const float* __restrict__ f_wx, const float* __restrict__ f_b,
            const float* __restrict__ p_wh, const float* __restrict__ p_wx, const float* __restrict__ p_b,
            const float* __restrict__ c_wh, const float* __restrict__ c_wx, const float* __restrict__ c_b,
            const float* __restrict__ o_wh, const float* __restrict__ o_wx, const float* __restrict__ o_b,
            float* __restrict__ out, uint32_t* __restrict__ flags, uint32_t* __restrict__ sbuf)
{
    __shared__ __align__(16) uint8_t lds[65536];
    uint8_t* WH = lds;                    // [4 gates][16 cols][256 k] bf16, XOR-swizzled   (32768 B)
    uint8_t* WX = lds + 32768;            // [4 gates][16 cols][128 k] bf16, swizzled       (16384 B)
    uint8_t* SL = lds + 49152;            // s tile [16][256] bf16 swz                      (8192 B)
    uint8_t* XT = lds + 57344;            // xt tile [16][128] bf16 swz (separate! no alias)(4096 B)
    float*   GB = (float*)(lds + 61440);  // activated gates [4][16][16] f32                (4096 B)

    const int tid  = (int)threadIdx.x;
    const int lane = tid & 63;
    const int wv   = tid >> 6;            // 0=forget,1=pot(tanh),2=perc,3=out
    const int blk  = (int)blockIdx.x;
    const int grp  = blk & 15;            // row-group
    const int cwg  = blk >> 4;            // column slice (this WG is producer #cwg of group grp)
    const int grow0 = grp << 4;           // first batch row
    const int hc0   = cwg << 4;           // first H column

    uint32_t* gflags = flags + grp * 32;  // 16 flag dwords per group, groups 128B apart

    const float* wh = (wv == 0) ? f_wh : (wv == 1) ? p_wh : (wv == 2) ? c_wh : o_wh;
    const float* wx = (wv == 0) ? f_wx : (wv == 1) ? p_wx : (wv == 2) ? c_wx : o_wx;
    const float* bp = (wv == 0) ? f_b  : (wv == 1) ? p_b  : (wv == 2) ? c_b  : o_b;

    // ---- stage weights into LDS: layout [gate][col][k] bf16, byte-off XOR ((col&7)<<4) ----
    {
        const int col = lane & 15, kc = lane >> 4;
        const uint32_t csw = (uint32_t)((col & 7) << 4);
        uint8_t* whb = WH + (size_t)(wv * 16 + col) * 512;
        #pragma unroll
        for (int it = 0; it < 8; ++it) {
            const int k0 = it * 32 + kc * 8;
            float v0 = wh[(size_t)(k0 + 0) * H_DIM + hc0 + col];
            float v1 = wh[(size_t)(k0 + 1) * H_DIM + hc0 + col];
            float v2 = wh[(size_t)(k0 + 2) * H_DIM + hc0 + col];
            float v3 = wh[(size_t)(k0 + 3) * H_DIM + hc0 + col];
            float v4 = wh[(size_t)(k0 + 4) * H_DIM + hc0 + col];
            float v5 = wh[(size_t)(k0 + 5) * H_DIM + hc0 + col];
            float v6 = wh[(size_t)(k0 + 6) * H_DIM + hc0 + col];
            float v7 = wh[(size_t)(k0 + 7) * H_DIM + hc0 + col];
            uint4 pk;
            pk.x = pk2bf(v0, v1); pk.y = pk2bf(v2, v3);
            pk.z = pk2bf(v4, v5); pk.w = pk2bf(v6, v7);
            *(uint4*)(whb + (((uint32_t)(it * 64 + kc * 16)) ^ csw)) = pk;
        }
        uint8_t* wxb = WX + (size_t)(wv * 16 + col) * 256;
        #pragma unroll
        for (int it = 0; it < 4; ++it) {
            const int k0 = it * 32 + kc * 8;
            float v0 = wx[(size_t)(k0 + 0) * H_DIM + hc0 + col];
            float v1 = wx[(size_t)(k0 + 1) * H_DIM + hc0 + col];
            float v2 = wx[(size_t)(k0 + 2) * H_DIM + hc0 + col];
            float v3 = wx[(size_t)(k0 + 3) * H_DIM + hc0 + col];
            float v4 = wx[(size_t)(k0 + 4) * H_DIM + hc0 + col];
            float v5 = wx[(size_t)(k0 + 5) * H_DIM + hc0 + col];
            float v6 = wx[(size_t)(k0 + 6) * H_DIM + hc0 + col];
            float v7 = wx[(size_t)(k0 + 7) * H_DIM + hc0 + col];
            uint4 pk;
            pk.x = pk2bf(v0, v1); pk.y = pk2bf(v2, v3);
            pk.z = pk2bf(v4, v5); pk.w = pk2bf(v6, v7);
            *(uint4*)(wxb + (((uint32_t)(it * 64 + kc * 16)) ^ csw)) = pk;
        }
    }
    const float bias = bp[hc0 + (lane & 15)];

    // combine-thread mapping: one (row,col) element per thread; l lives in a register
    const int crow = tid >> 4, ccol = tid & 15;
    const uint32_t pub_idx = (uint32_t)(grow0 + crow) * 128u + (uint32_t)cwg * 8u + (uint32_t)(ccol >> 1);

    // zero-publish s(0)=0 into buffer 0, then raise own flag to 1 (fire-and-forget, no fence)
    if ((tid & 1) == 0)
        __hip_atomic_store(sbuf + pub_idx, 0u, __ATOMIC_RELAXED, __HIP_MEMORY_SCOPE_SYSTEM);
    asm volatile("s_waitcnt vmcnt(0)" ::: "memory");
    __syncthreads();
    if (tid == 0)
        __hip_atomic_store(gflags + cwg, 1u, __ATOMIC_RELAXED, __HIP_MEMORY_SCOPE_SYSTEM);

    // x prefetch for t=0
    const int xrow = tid >> 4, xseg = tid & 15;
    const uint32_t xsw = (uint32_t)((xrow & 7) << 4);
    const float* xptr = x + (size_t)(grow0 + xrow) * (T_STEPS * I_DIM) + xseg * 8;
    float4 xr0 = *(const float4*)(xptr);
    float4 xr1 = *(const float4*)(xptr + 4);

    // per-lane fragment bases (A row / B col both = lane&15)
    const int fr = lane & 15, fkc = lane >> 4;
    const uint32_t fsw = (uint32_t)((fr & 7) << 4);
    uint8_t* slA = SL + (size_t)fr * 512;
    uint8_t* xtA = XT + (size_t)fr * 256;
    uint8_t* whB = WH + (size_t)(wv * 16 + fr) * 512;
    uint8_t* wxB = WX + (size_t)(wv * 16 + fr) * 256;

    // this thread gathers 32B of s-row (grow0+xrow), cols [xseg*16, xseg*16+16) -> producer #xseg
    uint32_t* myflag = gflags + xseg;

    float l_reg = 0.f, s_fin = 0.f, l_fin = 0.f;

    for (int t = 0; t < T_STEPS; ++t) {
        // stage xt(t) (bf16) into XT
        {
            uint4 pk;
            pk.x = pk2bf(xr0.x, xr0.y); pk.y = pk2bf(xr0.z, xr0.w);
            pk.z = pk2bf(xr1.x, xr1.y); pk.w = pk2bf(xr1.z, xr1.w);
            *(uint4*)(XT + (size_t)xrow * 256 + (((uint32_t)(xseg * 16)) ^ xsw)) = pk;
        }
        // prefetch x(t+1)
        {
            const int tn = (t + 1 < T_STEPS) ? (t + 1) : (T_STEPS - 1);
            const float* p = xptr + (size_t)tn * I_DIM;
            xr0 = *(const float4*)(p);
            xr1 = *(const float4*)(p + 4);
        }
        __syncthreads();  // B1: xt tile ready (also orders SL overwrite vs prev-step readers)

        // spin until my producer published s(t); 4 lanes/wave share a flag dword -> 1 coalesced req
        {
            const uint32_t target = (uint32_t)t + 1u;
            while (__hip_atomic_load(myflag, __ATOMIC_RELAXED, __HIP_MEMORY_SCOPE_SYSTEM) < target) {}
        }
        asm volatile("" ::: "memory");
        // issue gather of my 32B (coherent sc0 sc1, bypass L1/L2 -> reads LLC)
        uint4 g0, g1;
        {
            const uint32_t* src = sbuf + (size_t)(t & 1) * 32768 + (size_t)(grow0 + xrow) * 128 + xseg * 8;
            asm volatile("global_load_dwordx4 %0, %1, off sc0 sc1" : "=v"(g0) : "v"(src) : "memory");
            asm volatile("global_load_dwordx4 %0, %1, off offset:16 sc0 sc1" : "=v"(g1) : "v"(src) : "memory");
        }
        // x-part MFMAs overlap with gather latency
        f32x4 acc = {0.f, 0.f, 0.f, 0.f};
        #pragma unroll
        for (int q = 0; q < 4; ++q) {
            const uint32_t o = (uint32_t)(q * 64 + fkc * 16);
            uint4 av = *(const uint4*)(xtA + (o ^ fsw));
            uint4 bv = *(const uint4*)(wxB + (o ^ fsw));
            acc = __builtin_amdgcn_mfma_f32_16x16x32_bf16(
                __builtin_bit_cast(bf16x8, av), __builtin_bit_cast(bf16x8, bv), acc, 0, 0, 0);
        }
        // land gather -> SL
        asm volatile("s_waitcnt vmcnt(0)" ::: "memory");
        __builtin_amdgcn_sched_barrier(0);
        {
            uint8_t* dst = SL + (size_t)xrow * 512;
            const uint32_t o = (uint32_t)(xseg * 32);
            *(uint4*)(dst + (o ^ xsw)) = g0;
            *(uint4*)(dst + ((o + 16) ^ xsw)) = g1;
        }
        __syncthreads();  // B2: s tile ready
        // recurrent MFMAs
        #pragma unroll
        for (int q = 0; q < 8; ++q) {
            const uint32_t o = (uint32_t)(q * 64 + fkc * 16);
            uint4 av = *(const uint4*)(slA + (o ^ fsw));
            uint4 bv = *(const uint4*)(whB + (o ^ fsw));
            acc = __builtin_amdgcn_mfma_f32_16x16x32_bf16(
                __builtin_bit_cast(bf16x8, av), __builtin_bit_cast(bf16x8, bv), acc, 0, 0, 0);
        }
        // bias + activation -> GB   (D layout: col=lane&15, row=(lane>>4)*4+j)
        #pragma unroll
        for (int j = 0; j < 4; ++j) {
            const float pre = acc[j] + bias;
            const float a = (wv == 1) ? tanh_(pre) : sigmoid_(pre);
            GB[wv * 256 + (fkc * 4 + j) * 16 + fr] = a;
        }
        __syncthreads();  // B3: all gates ready
        // combine (1 element per thread) + publish s_new slice
        {
            const float fg  = GB[0 * 256 + crow * 16 + ccol];
            const float pot = GB[1 * 256 + crow * 16 + ccol];
            const float prc = GB[2 * 256 + crow * 16 + ccol];
            const float og  = GB[3 * 256 + crow * 16 + ccol];
            const float lnew = fg * l_reg + prc * pot;
            const float snew = tanh_(lnew) * og;
            l_reg = lnew;
            if (t == T_STEPS - 1) { s_fin = snew; l_fin = lnew; }
            const uint32_t sb = f2bf(snew);
            const uint32_t ob = (uint32_t)__shfl_xor((int)sb, 1, 64);
            if (((tid & 1) == 0) && (t != T_STEPS - 1)) {
                const uint32_t pkd = (sb & 0xFFFFu) | (ob << 16);
                __hip_atomic_store(sbuf + (size_t)((t + 1) & 1) * 32768 + pub_idx, pkd,
                                   __ATOMIC_RELAXED, __HIP_MEMORY_SCOPE_SYSTEM);
            }
        }
        if (t != T_STEPS - 1) {
            // drain publish stores to the coherence point, then raise flag (fire-and-forget)
            asm volatile("s_waitcnt vmcnt(0)" ::: "memory");
            __syncthreads();  // B4
            if (tid == 0)
                __hip_atomic_store(gflags + cwg, (uint32_t)t + 2u,
                                   __ATOMIC_RELAXED, __HIP_MEMORY_SCOPE_SYSTEM);
        }
    }

    // outputs: short_term then long_term, [256][256] f32 each
    out[(size_t)(grow0 + crow) * H_DIM + hc0 + ccol] = s_fin;
    out[(size_t)H_DIM * H_DIM + (size_t)(grow0 + crow) * H_DIM + hc0 + ccol] = l_fin;
}

extern "C" void kernel_launch(void* const* d_in, const int* in_sizes, int n_in,
                              void* d_out, int out_size, void* d_ws, size_t ws_size,
                              hipStream_t stream) {
    const float* x    = (const float*)d_in[0];
    const float* f_wh = (const float*)d_in[1];
    const float* f_wx = (const float*)d_in[2];
    const float* f_b  = (const float*)d_in[3];
    const float* p_wh = (const float*)d_in[4];
    const float* p_wx = (const float*)d_in[5];
    const float* p_b  = (const float*)d_in[6];
    const float* c_wh = (const float*)d_in[7];
    const float* c_wx = (const float*)d_in[8];
    const float* c_b  = (const float*)d_in[9];
    const float* o_wh = (const float*)d_in[10];
    const float* o_wx = (const float*)d_in[11];
    const float* o_b  = (const float*)d_in[12];
    float* outp = (float*)d_out;
    uint32_t* flags = (uint32_t*)d_ws;
    uint32_t* sbuf  = (uint32_t*)((char*)d_ws + 4096);   // 2 x 256x256 bf16 = 256 KiB

    // flags must be zero every call (graph replays)
    hipMemsetAsync(d_ws, 0, 4096, stream);

    void* args[] = { (void*)&x,
                     (void*)&f_wh, (void*)&f_wx, (void*)&f_b,
                     (void*)&p_wh, (void*)&p_wx, (void*)&p_b,
                     (void*)&c_wh, (void*)&c_wx, (void*)&c_b,
                     (void*)&o_wh, (void*)&o_wx, (void*)&o_b,
                     (void*)&outp, (void*)&flags, (void*)&sbuf };
    hipLaunchCooperativeKernel((const void*)lstm_kernel, dim3(256), dim3(256), args, 0, stream);
}

// Round 4
// 1947.092 us; speedup vs baseline: 3.8202x; 1.1817x over previous
//
#include <hip/hip_runtime.h>
#include <cstdint>

#define T_STEPS 1024
#define I_DIM 128
#define H_DIM 256
// grid: 256 blocks = 16 column-slices (cwg) x 16 row-groups (grp); 256 threads = 4 waves = 4 gates
// ws layout: [4096, 4096+2*262144): tagged exchange buffers
//   slot(parity,row,cp) = 8 bytes [2xbf16 data | u32 tag] at parity*262144 + row*1024 + cp*8
// All exchange traffic is LLC-scope (sc0 sc1): no placement or hwreg assumptions, every wait
// is on an LLC-coherent location -> deadlock-free regardless of scheduling.

typedef __attribute__((ext_vector_type(8))) short bf16x8;
typedef __attribute__((ext_vector_type(4))) float f32x4;
typedef __attribute__((ext_vector_type(2))) unsigned int u32x2;

__device__ __forceinline__ uint32_t f2bf(float f) {
    uint32_t u = __builtin_bit_cast(uint32_t, f);
    return (u + 0x7FFFu + ((u >> 16) & 1u)) >> 16;   // RNE
}
__device__ __forceinline__ uint32_t pk2bf(float lo, float hi) {
    return (f2bf(lo) & 0xFFFFu) | (f2bf(hi) << 16);
}
__device__ __forceinline__ float sigmoid_(float v) { return 1.f / (1.f + __expf(-v)); }
__device__ __forceinline__ float tanh_(float v) { float e = __expf(2.f * v); return 1.f - 2.f / (e + 1.f); }

__global__ void __launch_bounds__(256, 1)
lstm_kernel(const float* __restrict__ x,
            const float* __restrict__ f_wh, const float* __restrict__ f_wx, const float* __restrict__ f_b,
            const float* __restrict__ p_wh, const float* __restrict__ p_wx, const float* __restrict__ p_b,
            const float* __restrict__ c_wh, const float* __restrict__ c_wx, const float* __restrict__ c_b,
            const float* __restrict__ o_wh, const float* __restrict__ o_wx, const float* __restrict__ o_b,
            float* __restrict__ out, uint8_t* __restrict__ ws)
{
    __shared__ __align__(16) uint8_t lds[65792];
    uint8_t* WH = lds;                    // [4 gates][16 cols][512B] bf16, XOR-swizzled  (32768 B)
    uint8_t* WX = lds + 32768;            // [4 gates][16 cols][256B] bf16, swizzled      (16384 B)
    uint8_t* SL = lds + 49152;            // s tile, 16 rows x 512B, XOR-swizzled         (8192 B)
    uint8_t* XT = lds + 57344;            // xt tile, 16 rows x 256B, XOR-swizzled        (4096 B)
    float*   GB = (float*)(lds + 61440);  // gates [4][16 x 17-pad floats]                (4352 B)

    const int tid  = (int)threadIdx.x;
    const int lane = tid & 63;
    const int wv   = tid >> 6;            // 0=forget,1=pot(tanh),2=perc,3=out
    const int blk  = (int)blockIdx.x;
    const int grp  = blk & 15;            // row-group
    const int cwg  = blk >> 4;            // column slice
    const int grow0 = grp << 4;           // first batch row
    const int hc0   = cwg << 4;           // first H column

    uint8_t* sbase = ws + 4096;

    const float* wh = (wv == 0) ? f_wh : (wv == 1) ? p_wh : (wv == 2) ? c_wh : o_wh;
    const float* wx = (wv == 0) ? f_wx : (wv == 1) ? p_wx : (wv == 2) ? c_wx : o_wx;
    const float* bp = (wv == 0) ? f_b  : (wv == 1) ? p_b  : (wv == 2) ? c_b  : o_b;

    // ---- stage weights into LDS: [gate][col][k] bf16, byte-off XOR ((col&7)<<4) ----
    {
        const int col = lane & 15, kc = lane >> 4;
        const uint32_t csw = (uint32_t)((col & 7) << 4);
        uint8_t* whb = WH + (size_t)(wv * 16 + col) * 512;
        #pragma unroll
        for (int it = 0; it < 8; ++it) {
            const int k0 = it * 32 + kc * 8;
            float v0 = wh[(size_t)(k0 + 0) * H_DIM + hc0 + col];
            float v1 = wh[(size_t)(k0 + 1) * H_DIM + hc0 + col];
            float v2 = wh[(size_t)(k0 + 2) * H_DIM + hc0 + col];
            float v3 = wh[(size_t)(k0 + 3) * H_DIM + hc0 + col];
            float v4 = wh[(size_t)(k0 + 4) * H_DIM + hc0 + col];
            float v5 = wh[(size_t)(k0 + 5) * H_DIM + hc0 + col];
            float v6 = wh[(size_t)(k0 + 6) * H_DIM + hc0 + col];
            float v7 = wh[(size_t)(k0 + 7) * H_DIM + hc0 + col];
            uint4 pk;
            pk.x = pk2bf(v0, v1); pk.y = pk2bf(v2, v3);
            pk.z = pk2bf(v4, v5); pk.w = pk2bf(v6, v7);
            *(uint4*)(whb + (((uint32_t)(it * 64 + kc * 16)) ^ csw)) = pk;
        }
        uint8_t* wxb = WX + (size_t)(wv * 16 + col) * 256;
        #pragma unroll
        for (int it = 0; it < 4; ++it) {
            const int k0 = it * 32 + kc * 8;
            float v0 = wx[(size_t)(k0 + 0) * H_DIM + hc0 + col];
            float v1 = wx[(size_t)(k0 + 1) * H_DIM + hc0 + col];
            float v2 = wx[(size_t)(k0 + 2) * H_DIM + hc0 + col];
            float v3 = wx[(size_t)(k0 + 3) * H_DIM + hc0 + col];
            float v4 = wx[(size_t)(k0 + 4) * H_DIM + hc0 + col];
            float v5 = wx[(size_t)(k0 + 5) * H_DIM + hc0 + col];
            float v6 = wx[(size_t)(k0 + 6) * H_DIM + hc0 + col];
            float v7 = wx[(size_t)(k0 + 7) * H_DIM + hc0 + col];
            uint4 pk;
            pk.x = pk2bf(v0, v1); pk.y = pk2bf(v2, v3);
            pk.z = pk2bf(v4, v5); pk.w = pk2bf(v6, v7);
            *(uint4*)(wxb + (((uint32_t)(it * 64 + kc * 16)) ^ csw)) = pk;
        }
    }
    const float bias = bp[hc0 + (lane & 15)];
    __syncthreads();   // staging complete

    // per-lane fragment bases (A row / B col both = lane&15)
    const int fr = lane & 15, fkc = lane >> 4;
    const uint32_t fsw = (uint32_t)((fr & 7) << 4);
    uint8_t* slA = SL + (size_t)fr * 512;
    uint8_t* xtA = XT + (size_t)fr * 256;
    const uint8_t* whB = WH + (size_t)(wv * 16 + fr) * 512;
    const uint8_t* wxB = WX + (size_t)(wv * 16 + fr) * 256;

    // preload loop-invariant B fragments (weights) into VGPRs
    uint4 bwh[8], bwx[4];
    #pragma unroll
    for (int q = 0; q < 8; ++q)
        bwh[q] = *(const uint4*)(whB + (((uint32_t)(q * 64 + fkc * 16)) ^ fsw));
    #pragma unroll
    for (int q = 0; q < 4; ++q)
        bwx[q] = *(const uint4*)(wxB + (((uint32_t)(q * 64 + fkc * 16)) ^ fsw));

    // combine-thread mapping: one (row,col) element per thread; l lives in a register
    const int crow = tid >> 4, ccol = tid & 15;

    // init publish: s_0 = 0, tag 1, parity 0 (fire-and-forget; consumers poll)
    if ((tid & 1) == 0) {
        uint8_t* pdst = sbase + (size_t)(grow0 + crow) * 1024 + (size_t)(cwg * 8 + (ccol >> 1)) * 8;
        u32x2 pd; pd.x = 0u; pd.y = 1u;
        asm volatile("global_store_dwordx2 %0, %1, off sc0 sc1" :: "v"(pdst), "v"(pd) : "memory");
    }

    // x prefetch for t=0
    const int xrow = tid >> 4, xseg = tid & 15;
    const uint32_t xsw = (uint32_t)((xrow & 7) << 4);
    const float* xptr = x + (size_t)(grow0 + xrow) * (T_STEPS * I_DIM) + xseg * 8;
    float4 xr0 = *(const float4*)(xptr);
    float4 xr1 = *(const float4*)(xptr + 4);

    float l_reg = 0.f, s_fin = 0.f, l_fin = 0.f;

    for (int t = 0; t < T_STEPS; ++t) {
        // stage xt(t) (bf16) into XT
        {
            uint4 pk;
            pk.x = pk2bf(xr0.x, xr0.y); pk.y = pk2bf(xr0.z, xr0.w);
            pk.z = pk2bf(xr1.x, xr1.y); pk.w = pk2bf(xr1.z, xr1.w);
            *(uint4*)(XT + (size_t)xrow * 256 + (((uint32_t)(xseg * 16)) ^ xsw)) = pk;
        }
        // prefetch x(t+1)
        {
            const int tn = (t + 1 < T_STEPS) ? (t + 1) : (T_STEPS - 1);
            const float* p = xptr + (size_t)tn * I_DIM;
            xr0 = *(const float4*)(p);
            xr1 = *(const float4*)(p + 4);
        }
        __syncthreads();  // B1: xt tile ready (also orders SL overwrite vs prev-step readers)

        // x-part MFMAs (independent of s)
        f32x4 accA = {0.f, 0.f, 0.f, 0.f};
        #pragma unroll
        for (int q = 0; q < 4; ++q) {
            uint4 av = *(const uint4*)(xtA + (((uint32_t)(q * 64 + fkc * 16)) ^ fsw));
            accA = __builtin_amdgcn_mfma_f32_16x16x32_bf16(
                __builtin_bit_cast(bf16x8, av), __builtin_bit_cast(bf16x8, bwx[q]), accA, 0, 0, 0);
        }

        // poll my producer's 8 tagged slots (row grow0+xrow, cols [xseg*16, +16))
        // detection and gather are the same LLC round trip; accept when all 8 tags == t+1
        uint4 g0, g1, g2, g3;
        uint32_t m;
        const uint32_t e = (uint32_t)t + 1u;
        const uint8_t* src = sbase + (size_t)((t & 1) ? 262144 : 0)
                           + (size_t)(grow0 + xrow) * 1024 + (size_t)xseg * 64;
        do {
            asm volatile("global_load_dwordx4 %0, %1, off sc0 sc1"
                         : "=v"(g0) : "v"(src) : "memory");
            asm volatile("global_load_dwordx4 %0, %1, off offset:16 sc0 sc1"
                         : "=v"(g1) : "v"(src) : "memory");
            asm volatile("global_load_dwordx4 %0, %1, off offset:32 sc0 sc1"
                         : "=v"(g2) : "v"(src) : "memory");
            asm volatile("global_load_dwordx4 %0, %1, off offset:48 sc0 sc1"
                         : "=v"(g3) : "v"(src) : "memory");
            asm volatile("s_waitcnt vmcnt(0)" ::: "memory");
            __builtin_amdgcn_sched_barrier(0);
            m = (g0.y ^ e) | (g0.w ^ e) | (g1.y ^ e) | (g1.w ^ e)
              | (g2.y ^ e) | (g2.w ^ e) | (g3.y ^ e) | (g3.w ^ e);
        } while (m != 0);

        // scatter accepted data into SL
        {
            uint4 d0; d0.x = g0.x; d0.y = g0.z; d0.z = g1.x; d0.w = g1.z;
            uint4 d1; d1.x = g2.x; d1.y = g2.z; d1.z = g3.x; d1.w = g3.z;
            uint8_t* dst = SL + (size_t)xrow * 512;
            const uint32_t o = (uint32_t)(xseg * 32);
            *(uint4*)(dst + (o ^ xsw)) = d0;
            *(uint4*)(dst + ((o + 16) ^ xsw)) = d1;
        }
        __syncthreads();  // B2: s tile ready

        // recurrent MFMAs, two independent accumulator chains
        f32x4 accB = {0.f, 0.f, 0.f, 0.f};
        #pragma unroll
        for (int q = 0; q < 4; ++q) {
            uint4 a0 = *(const uint4*)(slA + (((uint32_t)(q * 64 + fkc * 16)) ^ fsw));
            uint4 a1 = *(const uint4*)(slA + (((uint32_t)((q + 4) * 64 + fkc * 16)) ^ fsw));
            accA = __builtin_amdgcn_mfma_f32_16x16x32_bf16(
                __builtin_bit_cast(bf16x8, a0), __builtin_bit_cast(bf16x8, bwh[q]), accA, 0, 0, 0);
            accB = __builtin_amdgcn_mfma_f32_16x16x32_bf16(
                __builtin_bit_cast(bf16x8, a1), __builtin_bit_cast(bf16x8, bwh[q + 4]), accB, 0, 0, 0);
        }

        // bias + activation -> GB (padded stride 17 floats; 2-way banks = free)
        #pragma unroll
        for (int j = 0; j < 4; ++j) {
            const float pre = accA[j] + accB[j] + bias;
            const float a = (wv == 1) ? tanh_(pre) : sigmoid_(pre);
            GB[wv * 272 + (fkc * 4 + j) * 17 + fr] = a;
        }
        __syncthreads();  // B3: all gates ready

        // combine (1 element per thread) + publish s_new slice (tagged, fire-and-forget)
        {
            const float fg  = GB[0 * 272 + crow * 17 + ccol];
            const float pot = GB[1 * 272 + crow * 17 + ccol];
            const float prc = GB[2 * 272 + crow * 17 + ccol];
            const float og  = GB[3 * 272 + crow * 17 + ccol];
            const float lnew = fg * l_reg + prc * pot;
            const float snew = tanh_(lnew) * og;
            l_reg = lnew;
            if (t == T_STEPS - 1) { s_fin = snew; l_fin = lnew; }
            const uint32_t sb = f2bf(snew);
            const uint32_t ob = (uint32_t)__shfl_xor((int)sb, 1, 64);
            if (((tid & 1) == 0) && (t != T_STEPS - 1)) {
                uint8_t* pdst = sbase + (size_t)(((t + 1) & 1) ? 262144 : 0)
                              + (size_t)(grow0 + crow) * 1024 + (size_t)(cwg * 8 + (ccol >> 1)) * 8;
                u32x2 pd; pd.x = (sb & 0xFFFFu) | (ob << 16); pd.y = (uint32_t)t + 2u;
                asm volatile("global_store_dwordx2 %0, %1, off sc0 sc1" :: "v"(pdst), "v"(pd) : "memory");
            }
        }
        // no drain, no flag, no 4th barrier
    }

    // outputs: short_term then long_term, [256][256] f32 each
    out[(size_t)(grow0 + crow) * H_DIM + hc0 + ccol] = s_fin;
    out[(size_t)H_DIM * H_DIM + (size_t)(grow0 + crow) * H_DIM + hc0 + ccol] = l_fin;
}

extern "C" void kernel_launch(void* const* d_in, const int* in_sizes, int n_in,
                              void* d_out, int out_size, void* d_ws, size_t ws_size,
                              hipStream_t stream) {
    const float* x    = (const float*)d_in[0];
    const float* f_wh = (const float*)d_in[1];
    const float* f_wx = (const float*)d_in[2];
    const float* f_b  = (const float*)d_in[3];
    const float* p_wh = (const float*)d_in[4];
    const float* p_wx = (const float*)d_in[5];
    const float* p_b  = (const float*)d_in[6];
    const float* c_wh = (const float*)d_in[7];
    const float* c_wx = (const float*)d_in[8];
    const float* c_b  = (const float*)d_in[9];
    const float* o_wh = (const float*)d_in[10];
    const float* o_wx = (const float*)d_in[11];
    const float* o_b  = (const float*)d_in[12];
    float* outp = (float*)d_out;
    uint8_t* wsp = (uint8_t*)d_ws;

    // tags must be zero every call (graph replays leave stale tags)
    hipMemsetAsync(d_ws, 0, 4096 + 2 * 262144, stream);

    void* args[] = { (void*)&x,
                     (void*)&f_wh, (void*)&f_wx, (void*)&f_b,
                     (void*)&p_wh, (void*)&p_wx, (void*)&p_b,
                     (void*)&c_wh, (void*)&c_wx, (void*)&c_b,
                     (void*)&o_wh, (void*)&o_wx, (void*)&o_b,
                     (void*)&outp, (void*)&wsp };
    hipLaunchCooperativeKernel((const void*)lstm_kernel, dim3(256), dim3(256), args, 0, stream);
}